// Round 4
// baseline (86.978 us; speedup 1.0000x reference)
//
#include <hip/hip_runtime.h>

#define B_SZ 256
#define C_SZ 1152
#define MO   128            // M*O = 8*16
#define CSPL 32
#define CRNG (C_SZ / CSPL)  // 36 capsules per block
#define RB   9              // capsules staged per barrier round
#define NROUND (CRNG / RB)  // 4 rounds
#define CAPS_EPS 1e-8f

struct alignas(8) H4 { _Float16 h[4]; };

// ---------------------------------------------------------------------------
// K1: u_hat[c,b,mo] (fp16) + R=0 partial sums (uniform c weights = 1/8).
// grid = CSPL*32 (csp = blk>>5, b-tile = blk&31), block = 256 = 8 groups x 32.
// Group g owns b = bt*8+g; lane l owns mo = l*4 .. l*4+3.
// W is staged transposed (i-major) in LDS in rounds of RB=9 capsules:
// 9 independent float4 loads per thread per round (9x MLP), 2 barriers per
// round instead of per capsule (8 total vs 72).
__global__ __launch_bounds__(256) void caps_uhat(
    const float* __restrict__ u,     // [B,C,8]
    const float* __restrict__ W,     // [C,128,8]
    H4* __restrict__ uhat,           // [C,B,32]  (H4 units: 4 fp16)
    float* __restrict__ part0)       // [CSPL,B,128]
{
    const int bt  = blockIdx.x & 31;
    const int csp = blockIdx.x >> 5;
    const int tid = threadIdx.x;
    const int g   = tid >> 5;
    const int l   = tid & 31;
    const int b   = bt * 8 + g;
    const int mo4 = l * 4;

    // i-major transposed W for RB capsules; rows padded to 132 floats
    // (row = 528B, plane = 4224B: both 16B-aligned; 38016B total -> 4 blk/CU)
    __shared__ __align__(16) float wT[RB][8][132];

    float acc[4] = {0.f, 0.f, 0.f, 0.f};
    const int cbeg = csp * CRNG;
    const int wmo = tid >> 1, wi0 = (tid & 1) * 4;   // staging scatter coords

    for (int r = 0; r < NROUND; ++r) {
        const int c0 = cbeg + r * RB;
        __syncthreads();   // protect previous round's wT reads
        // ---- stage RB capsules: 9 back-to-back float4 loads per thread ----
        float4 wv[RB];
#pragma unroll
        for (int j = 0; j < RB; ++j)
            wv[j] = *reinterpret_cast<const float4*>(
                W + (size_t)(c0 + j) * 1024 + tid * 4);
#pragma unroll
        for (int j = 0; j < RB; ++j) {
            wT[j][wi0 + 0][wmo] = wv[j].x;
            wT[j][wi0 + 1][wmo] = wv[j].y;
            wT[j][wi0 + 2][wmo] = wv[j].z;
            wT[j][wi0 + 3][wmo] = wv[j].w;
        }
        __syncthreads();

        // ---- compute RB capsules ----
#pragma unroll
        for (int j = 0; j < RB; ++j) {
            const int c = c0 + j;
            const float4* up = reinterpret_cast<const float4*>(
                u + ((size_t)b * C_SZ + c) * 8);
            float4 u0 = up[0], u1 = up[1];
            float u8[8] = {u0.x, u0.y, u0.z, u0.w, u1.x, u1.y, u1.z, u1.w};

            float uh[4] = {0.f, 0.f, 0.f, 0.f};
#pragma unroll
            for (int i = 0; i < 8; ++i) {
                float4 w4 = *reinterpret_cast<const float4*>(&wT[j][i][mo4]);
                uh[0] = fmaf(w4.x, u8[i], uh[0]);
                uh[1] = fmaf(w4.y, u8[i], uh[1]);
                uh[2] = fmaf(w4.z, u8[i], uh[2]);
                uh[3] = fmaf(w4.w, u8[i], uh[3]);
            }
            H4 hv;
            hv.h[0] = (_Float16)uh[0]; hv.h[1] = (_Float16)uh[1];
            hv.h[2] = (_Float16)uh[2]; hv.h[3] = (_Float16)uh[3];
            uhat[((size_t)c * B_SZ + b) * 32 + l] = hv;
#pragma unroll
            for (int k = 0; k < 4; ++k) acc[k] += uh[k];
        }
    }
    *reinterpret_cast<float4*>(part0 + ((size_t)csp * B_SZ + b) * MO + mo4) =
        make_float4(acc[0] * 0.125f, acc[1] * 0.125f,
                    acc[2] * 0.125f, acc[3] * 0.125f);
}

// ---------------------------------------------------------------------------
// vcalc: vout = squash(sum_k part_in[k]) (+ addv if non-null).
// grid = B, block = 128.
__global__ __launch_bounds__(128) void caps_vcalc(
    const float* __restrict__ part_in,  // [CSPL,B,128]
    const float* __restrict__ addv,     // [B,128] or null
    float* __restrict__ vout)           // [B,128]
{
    const int b = blockIdx.x, t = threadIdx.x;
    float s = 0.f;
#pragma unroll
    for (int k = 0; k < CSPL; ++k)
        s += part_in[((size_t)k * B_SZ + b) * MO + t];
    float n2 = s * s;                   // 16-lane group = one m row
    n2 += __shfl_xor(n2, 1);
    n2 += __shfl_xor(n2, 2);
    n2 += __shfl_xor(n2, 4);
    n2 += __shfl_xor(n2, 8);
    float norm = sqrtf(n2);
    float v = (n2 / (1.f + n2)) * s / (norm + CAPS_EPS);
    if (addv) v += addv[(size_t)b * MO + t];
    vout[(size_t)b * MO + t] = v;
}

// ---------------------------------------------------------------------------
// route: one routing pass over materialized u_hat.
__global__ __launch_bounds__(256) void caps_route(
    const H4* __restrict__ uhat,        // [C,B,32]
    const float* __restrict__ vbuf,     // [B,128]
    float* __restrict__ part_out)       // [CSPL,B,128]
{
    const int bt  = blockIdx.x & 31;
    const int csp = blockIdx.x >> 5;
    const int tid = threadIdx.x;
    const int g   = tid >> 5;
    const int l   = tid & 31;
    const int b   = bt * 8 + g;
    const int mo4 = l * 4;

    const float4 v4 = *reinterpret_cast<const float4*>(
        vbuf + (size_t)b * MO + mo4);
    float acc[4] = {0.f, 0.f, 0.f, 0.f};

    const int cbeg = csp * CRNG, cend = cbeg + CRNG;
    const H4* base = uhat + (size_t)b * 32 + l;  // stride B_SZ*32 per c

    H4 r0 = base[(size_t)cbeg * B_SZ * 32];
    H4 r1 = base[(size_t)(cbeg + 1) * B_SZ * 32];

    for (int c = cbeg; c < cend; c += 2) {
        H4 n0 = r0, n1 = r1;
        if (c + 2 < cend) {
            n0 = base[(size_t)(c + 2) * B_SZ * 32];
            n1 = base[(size_t)(c + 3) * B_SZ * 32];
        }
#pragma unroll
        for (int q = 0; q < 2; ++q) {
            H4 r = q ? r1 : r0;
            float uh0 = (float)r.h[0], uh1 = (float)r.h[1];
            float uh2 = (float)r.h[2], uh3 = (float)r.h[3];
            float uv = uh0 * v4.x + uh1 * v4.y + uh2 * v4.z + uh3 * v4.w;
            uv += __shfl_xor(uv, 1);          // reduce over o-quarters
            uv += __shfl_xor(uv, 2);          // -> uv[m] on 4 lanes
            float mx = fmaxf(uv, __shfl_xor(uv, 4));
            mx = fmaxf(mx, __shfl_xor(mx, 8));
            mx = fmaxf(mx, __shfl_xor(mx, 16));
            float e = expf(uv - mx);
            float den = e;
            den += __shfl_xor(den, 4);
            den += __shfl_xor(den, 8);
            den += __shfl_xor(den, 16);
            float cw = e / den;
            acc[0] = fmaf(cw, uh0, acc[0]);
            acc[1] = fmaf(cw, uh1, acc[1]);
            acc[2] = fmaf(cw, uh2, acc[2]);
            acc[3] = fmaf(cw, uh3, acc[3]);
        }
        r0 = n0; r1 = n1;
    }
    *reinterpret_cast<float4*>(part_out + ((size_t)csp * B_SZ + b) * MO + mo4) =
        make_float4(acc[0], acc[1], acc[2], acc[3]);
}

// ---------------------------------------------------------------------------
// Fallback (small-ws): round-1 fused kernel, needs only 384 KB of ws.
template <int R>
__global__ __launch_bounds__(256) void caps_small(
    const float* __restrict__ u, const float* __restrict__ W,
    const float* __restrict__ s_in, const float* __restrict__ v0_in,
    float* __restrict__ s_out, float* __restrict__ v0_out,
    float* __restrict__ out)
{
    const int b = blockIdx.x, tid = threadIdx.x;
    __shared__ float sh_v[8][17];
    __shared__ float sh_part[256][17];

    if (R >= 1) {
        if (tid < 128) {
            float val = s_in[b * 128 + tid];
            float n2 = val * val;
            n2 += __shfl_xor(n2, 1); n2 += __shfl_xor(n2, 2);
            n2 += __shfl_xor(n2, 4); n2 += __shfl_xor(n2, 8);
            float norm = sqrtf(n2);
            float v = (n2 / (1.f + n2)) * val / (norm + CAPS_EPS);
            int m = tid >> 4, o = tid & 15;
            if (R == 1) { v0_out[b * 128 + tid] = v; sh_v[m][o] = v; }
            else        { sh_v[m][o] = v + v0_in[b * 128 + tid]; }
        }
        __syncthreads();
    }
    const int c_local = tid >> 3, m = tid & 7;
    float s_acc[16];
#pragma unroll
    for (int o = 0; o < 16; ++o) s_acc[o] = 0.f;
    for (int cc = 0; cc < C_SZ; cc += 32) {
        const int c = cc + c_local;
        const float4* up = reinterpret_cast<const float4*>(
            u + (size_t)(b * C_SZ + c) * 8);
        float4 u0 = up[0], u1 = up[1];
        float u8[8] = {u0.x, u0.y, u0.z, u0.w, u1.x, u1.y, u1.z, u1.w};
        float uh[16];
        const float4* wp = reinterpret_cast<const float4*>(
            W + (size_t)((c * 8 + m) * 16) * 8);
#pragma unroll
        for (int o = 0; o < 16; ++o) {
            float4 w0 = wp[o * 2], w1 = wp[o * 2 + 1];
            uh[o] = w0.x * u8[0] + w0.y * u8[1] + w0.z * u8[2] + w0.w * u8[3] +
                    w1.x * u8[4] + w1.y * u8[5] + w1.z * u8[6] + w1.w * u8[7];
        }
        float cw;
        if (R == 0) cw = 0.125f;
        else {
            float uv = 0.f;
#pragma unroll
            for (int o = 0; o < 16; ++o) uv = fmaf(uh[o], sh_v[m][o], uv);
            float mx = uv;
            mx = fmaxf(mx, __shfl_xor(mx, 1));
            mx = fmaxf(mx, __shfl_xor(mx, 2));
            mx = fmaxf(mx, __shfl_xor(mx, 4));
            float e = expf(uv - mx);
            float den = e;
            den += __shfl_xor(den, 1); den += __shfl_xor(den, 2);
            den += __shfl_xor(den, 4);
            cw = e / den;
        }
#pragma unroll
        for (int o = 0; o < 16; ++o) s_acc[o] = fmaf(cw, uh[o], s_acc[o]);
    }
#pragma unroll
    for (int o = 0; o < 16; ++o) sh_part[tid][o] = s_acc[o];
    __syncthreads();
    if (tid < 128) {
        const int m2 = tid >> 4, o2 = tid & 15;
        float s = 0.f;
#pragma unroll
        for (int gg = 0; gg < 32; ++gg) s += sh_part[gg * 8 + m2][o2];
        if (R < 2) s_out[b * 128 + tid] = s;
        else {
            float n2 = s * s;
            n2 += __shfl_xor(n2, 1); n2 += __shfl_xor(n2, 2);
            n2 += __shfl_xor(n2, 4); n2 += __shfl_xor(n2, 8);
            float norm = sqrtf(n2);
            out[b * 128 + tid] = (n2 / (1.f + n2)) * s / (norm + CAPS_EPS);
        }
    }
}

extern "C" void kernel_launch(void* const* d_in, const int* in_sizes, int n_in,
                              void* d_out, int out_size, void* d_ws, size_t ws_size,
                              hipStream_t stream) {
    const float* u = (const float*)d_in[0];  // [256,1152,8]
    const float* W = (const float*)d_in[1];  // [1152,8,16,8]
    float* out = (float*)d_out;              // [256,8,16]

    const size_t UHAT_ELEMS = (size_t)C_SZ * B_SZ * 32;          // H4 units
    const size_t UHAT_BYTES = UHAT_ELEMS * 8;                    // 75.5 MB
    const size_t PART_FLOATS = (size_t)CSPL * B_SZ * MO;         // 4.19 MB
    const size_t NEED = UHAT_BYTES + 2 * PART_FLOATS * 4 + 2 * B_SZ * MO * 4;

    if (ws_size >= NEED) {
        H4* uhat     = (H4*)d_ws;
        float* partA = (float*)((char*)d_ws + UHAT_BYTES);
        float* partB = partA + PART_FLOATS;
        float* v0    = partB + PART_FLOATS;
        float* vsum  = v0 + B_SZ * MO;

        dim3 gridC(CSPL * 32), blk(256);
        caps_uhat <<<gridC, blk, 0, stream>>>(u, W, uhat, partA);
        caps_vcalc<<<dim3(B_SZ), dim3(128), 0, stream>>>(partA, nullptr, v0);
        caps_route<<<gridC, blk, 0, stream>>>(uhat, v0, partB);
        caps_vcalc<<<dim3(B_SZ), dim3(128), 0, stream>>>(partB, v0, vsum);
        caps_route<<<gridC, blk, 0, stream>>>(uhat, vsum, partA);
        caps_vcalc<<<dim3(B_SZ), dim3(128), 0, stream>>>(partA, nullptr, out);
    } else {
        // small-ws fallback (round-1 path)
        float* sA = (float*)d_ws;
        float* sB = sA + 32768;
        float* v0 = sB + 32768;
        dim3 grid(B_SZ), blk(256);
        caps_small<0><<<grid, blk, 0, stream>>>(u, W, nullptr, nullptr, sA, nullptr, nullptr);
        caps_small<1><<<grid, blk, 0, stream>>>(u, W, sA, nullptr, sB, v0, nullptr);
        caps_small<2><<<grid, blk, 0, stream>>>(u, W, sB, v0, nullptr, nullptr, out);
    }
}